// Round 1
// baseline (84.920 us; speedup 1.0000x reference)
//
#include <hip/hip_runtime.h>
#include <stdint.h>

// Problem constants: B=4, I=32, N=4096, D=64, TEM=1.0, WP=0.5
#define Bsz 4
#define Isz 32
#define Nsz 4096
#define Dsz 64
#define WPc 0.5f
#define ALPHA 1.2011224087864498f  // sqrt(log2(e)): folds 1/ln2 into the data
#define LN2 0.69314718055994531f
#define LSZ2 256                   // member-list capacity (mean 128, sd 11)
#define GBLK (Isz * Bsz * 2)       // gram grid: 2 row-chunks per (b,i)

typedef __attribute__((ext_vector_type(8))) short short8;   // 8 bf16
typedef __attribute__((ext_vector_type(4))) float floatx4;  // MFMA C/D

__device__ inline uint16_t f2bf(float f) {
  uint32_t u = __float_as_uint(f);
  u += 0x7fffu + ((u >> 16) & 1u);  // RNE
  return (uint16_t)(u >> 16);
}
// exp2 via raw v_exp_f32; same op in rowsum and gram so negtot-negSub cancels.
__device__ inline float exp2_raw(float f) { return __builtin_amdgcn_exp2f(f); }

// ---------------------------------------------------------------------------
// Kernel 1: build xbf, the MFMA-fragment-ordered bf16(ALPHA*x):
//   unit U = (tile_g*2 + kh)*64 + lane, lane = quad*16 + m, holds
//   x[tile_g*16 + m][kh*32 + quad*8 .. +7] as 8 bf16 (16 B).
// A wave's fragment load is then base + lane*16 -> one dense 1 KB
// global_load_dwordx4. Each thread converts one unit (reads 32B = 1 sector).
// Blocks 0..63 also zero negtot / accum / ticket. No row-major copy anymore.
// ---------------------------------------------------------------------------
__global__ __launch_bounds__(256) void prep_kernel(
    const float* __restrict__ x, uint4* __restrict__ xbf,
    float* __restrict__ negtot, float* __restrict__ accum,
    int* __restrict__ ticket) {
  const int gid = blockIdx.x * 256 + threadIdx.x;  // 0..131071 units
  const int m = gid & 15;
  const int quad = (gid >> 4) & 3;
  const int kh = (gid >> 6) & 1;
  const int tile_g = gid >> 7;  // global 16-row tile (spans batches)
  const size_t src = (size_t)(tile_g * 16 + m) * Dsz + kh * 32 + quad * 8;
  const float4 a = *(const float4*)(x + src);
  const float4 c = *(const float4*)(x + src + 4);
  ushort4 lo, hi;
  lo.x = f2bf(a.x * ALPHA); lo.y = f2bf(a.y * ALPHA);
  lo.z = f2bf(a.z * ALPHA); lo.w = f2bf(a.w * ALPHA);
  hi.x = f2bf(c.x * ALPHA); hi.y = f2bf(c.y * ALPHA);
  hi.z = f2bf(c.z * ALPHA); hi.w = f2bf(c.w * ALPHA);
  ushort4* dst = (ushort4*)(xbf + gid);
  dst[0] = lo;
  dst[1] = hi;

  if (blockIdx.x < 64) {
    negtot[gid] = 0.f;  // gid < 16384 here
    if (gid == 0) {
      accum[0] = 0.f;
      ticket[0] = 0;
    }
  }
}

// ---------------------------------------------------------------------------
// Kernel 2: SYMMETRIC exp-rowsum. sim = X X^T is symmetric and the bf16 MFMA
// dot product is bit-exact under A/B swap (same k-order, commutative
// products, same reduction tree), so exp2(sim[p][n]) computed once serves
// both negtot[p] (row sum, as before) and negtot[n] (column sum, via
// cross-quad shfl reduce + one 64B-contiguous atomic per col-tile).
// Work: only the 136 lower-triangle+diagonal 256x256 supertiles of 256
// per batch (0.53x MFMA / exp / traffic of the full sweep).
// One wave per 64x256 tile -> 64-thread blocks, 544 wave-units/batch,
// 2176 blocks total (8.5 blocks/CU, ~6% tail) for dynamic balance.
// Bit-chain (kh order, exp2_raw) identical to gram2 so negtot-negSub
// still cancels cleanly. C/D layout: col = lane&15, row = quad*4 + reg.
// ---------------------------------------------------------------------------
__global__ __launch_bounds__(64, 4) void rowsum_sym_kernel(
    const uint4* __restrict__ xbf, float* __restrict__ negtot) {
  const int lane = threadIdx.x;  // one wave per block
  const int quad = lane >> 4;
  const int l15 = lane & 15;

  const int b = blockIdx.y;
  const int wu = blockIdx.x;  // wave-unit within batch: 0..543
  const int st = wu >> 2;     // supertile 0..135
  const int w = wu & 3;       // 64-row chunk within supertile

  int R, C;
  if (st < 16) {
    R = st; C = st;  // diagonal supertile: compute full 256x256
  } else {
    const int t = st - 16;  // 0..119 -> (R,C) with R>C
    int r = (int)((1.0f + sqrtf((float)(8 * t + 1))) * 0.5f);
    if (r * (r - 1) / 2 > t) --r;
    else if (r * (r + 1) / 2 <= t) ++r;
    R = r;
    C = t - r * (r - 1) / 2;
  }
  const bool offdiag = (R != C);
  const int tb = b * 256;  // 16-row-tile base for this batch
  const size_t bN = (size_t)b * Nsz;

  // A fragments: this wave's 4 row-tiles (rows R*256 + w*64 .. +63)
  short8 af[4][2];
#pragma unroll
  for (int i = 0; i < 4; ++i) {
    const int tile = tb + R * 16 + w * 4 + i;
#pragma unroll
    for (int kh = 0; kh < 2; ++kh)
      af[i][kh] = *(const short8*)&xbf[(size_t)(tile * 2 + kh) * 64 + lane];
  }

  float negAll[4][4];
#pragma unroll
  for (int i = 0; i < 4; ++i)
#pragma unroll
    for (int r = 0; r < 4; ++r) negAll[i][r] = 0.f;

#pragma unroll 1
  for (int g = 0; g < 8; ++g) {  // 8 groups of 2 col-tiles (cols C*256..+255)
    short8 bf[2][2];
#pragma unroll
    for (int c = 0; c < 2; ++c) {
      const int tile = tb + C * 16 + g * 2 + c;
#pragma unroll
      for (int kh = 0; kh < 2; ++kh)
        bf[c][kh] = *(const short8*)&xbf[(size_t)(tile * 2 + kh) * 64 + lane];
    }
    floatx4 acc[4][2];
#pragma unroll
    for (int i = 0; i < 4; ++i)
#pragma unroll
      for (int c = 0; c < 2; ++c) acc[i][c] = (floatx4){0.f, 0.f, 0.f, 0.f};
#pragma unroll
    for (int kh = 0; kh < 2; ++kh)
#pragma unroll
      for (int c = 0; c < 2; ++c)
#pragma unroll
        for (int i = 0; i < 4; ++i)
          acc[i][c] = __builtin_amdgcn_mfma_f32_16x16x32_bf16(
              af[i][kh], bf[c][kh], acc[i][c], 0, 0, 0);
    if (offdiag) {
      // row sums AND column sums (symmetric partner rows in C-block)
      float colPart[2] = {0.f, 0.f};
#pragma unroll
      for (int c = 0; c < 2; ++c)
#pragma unroll
        for (int i = 0; i < 4; ++i)
#pragma unroll
          for (int r = 0; r < 4; ++r) {
            const float e = exp2_raw(acc[i][c][r]);
            negAll[i][r] += e;
            colPart[c] += e;
          }
#pragma unroll
      for (int c = 0; c < 2; ++c) {
        float s = colPart[c];
        s += __shfl_xor(s, 16, 64);  // reduce over the 4 quads (64 rows)
        s += __shfl_xor(s, 32, 64);
        if (quad == 0)
          atomicAdd(&negtot[bN + C * 256 + (g * 2 + c) * 16 + l15], s);
      }
    } else {
#pragma unroll
      for (int c = 0; c < 2; ++c)
#pragma unroll
        for (int i = 0; i < 4; ++i)
#pragma unroll
          for (int r = 0; r < 4; ++r) negAll[i][r] += exp2_raw(acc[i][c][r]);
    }
  }

  // row sums: reduce over the 16 l15 lanes; one atomic instr per (tile, reg)
  const int wrow0 = R * 256 + w * 64;
#pragma unroll
  for (int i = 0; i < 4; ++i)
#pragma unroll
    for (int r = 0; r < 4; ++r) {
      float g = negAll[i][r];
#pragma unroll
      for (int m = 1; m < 16; m <<= 1) g += __shfl_xor(g, m, 64);
      if (l15 == 0)
        atomicAdd(&negtot[bN + wrow0 + i * 16 + quad * 4 + r], g);
    }
}

// ---------------------------------------------------------------------------
// Kernel 3: per-instance Gram + finalize. Same as before: member rows are
// staged from xbf (row p, dims u*8..+7 live at unit
// ((p>>4)*2 + (u>>2))*64 + (u&3)*16 + (p&15)) -- same bf16 bits, same
// kh-chain as rowsum, so negtot - negSub cancels cleanly.
// ---------------------------------------------------------------------------
__global__ __launch_bounds__(256) void gram2_kernel(
    const uint4* __restrict__ xbf, const uint8_t* __restrict__ label,
    const float* __restrict__ negtot, float* __restrict__ accum,
    int* __restrict__ ticket, float* __restrict__ out) {
  __shared__ int list[LSZ2];
  __shared__ int scnt;
  __shared__ uint4 grow[LSZ2 * 8];  // 32 KB swizzled member-row data
  __shared__ float sPos[4];
  __shared__ float sLn[4];

  const int t = threadIdx.x;
  const int lane = t & 63;
  const int w = t >> 6;
  const int quad = lane >> 4;
  const int l15 = lane & 15;
  const int i = blockIdx.x;
  const int b = blockIdx.y;
  const int rc = blockIdx.z;  // row-chunk 0/1
  const size_t bN = (size_t)b * Nsz;
  const int tb = b * 256;

  if (t == 0) scnt = 0;
  __syncthreads();
  {  // membership: 16 label bytes per thread
    const uint4 lv = ((const uint4*)(label + ((size_t)b * Isz + i) * Nsz))[t];
    const uint32_t words[4] = {lv.x, lv.y, lv.z, lv.w};
#pragma unroll
    for (int jw = 0; jw < 4; ++jw)
#pragma unroll
      for (int jb = 0; jb < 4; ++jb) {
        if ((words[jw] >> (jb * 8)) & 0xff) {
          const int idx = atomicAdd(&scnt, 1);
          if (idx < LSZ2) list[idx] = t * 16 + jw * 4 + jb;
        }
      }
  }
  __syncthreads();
  const int cnt = scnt;
  const int cntE = cnt < LSZ2 ? cnt : LSZ2;

  // stage member rows into swizzled LDS from fragment-ordered xbf
  for (int s = t; s < cntE * 8; s += 256) {
    const int j = s >> 3, u = s & 7;
    const int p = list[j];
    const size_t unit =
        (size_t)((tb + (p >> 4)) * 2 + (u >> 2)) * 64 + (u & 3) * 16 + (p & 15);
    grow[(j << 3) | (u ^ (j & 7))] = xbf[unit];
  }
  __syncthreads();

  const bool active = (cnt >= 5) && (rc * 128 < cntE);
  if (active) {
    // A fragments for this block's 128 rows (wave w: rows rc*128+w*32..+31)
    short8 af[2][2];
#pragma unroll
    for (int rt = 0; rt < 2; ++rt) {
      int ridx = rc * 128 + w * 32 + rt * 16 + l15;
      ridx = ridx < cntE ? ridx : cntE - 1;
#pragma unroll
      for (int kh = 0; kh < 2; ++kh) {
        const int u = quad + kh * 4;
        af[rt][kh] = *(const short8*)&grow[(ridx << 3) | (u ^ (ridx & 7))];
      }
    }

    float pos = 0.f, lns = 0.f;
    float ngrow_acc[2][4] = {{0.f, 0.f, 0.f, 0.f}, {0.f, 0.f, 0.f, 0.f}};
    const int nch = (cntE + 127) >> 7;
    for (int cc = 0; cc < nch; ++cc) {
      short8 bfr[8][2];
      bool cvalid[8];
#pragma unroll
      for (int ct = 0; ct < 8; ++ct) {
        const int cidx0 = cc * 128 + ct * 16 + l15;
        const int cidx = cidx0 < cntE ? cidx0 : cntE - 1;
        cvalid[ct] = cidx0 < cntE;
#pragma unroll
        for (int kh = 0; kh < 2; ++kh) {
          const int u = quad + kh * 4;
          bfr[ct][kh] = *(const short8*)&grow[(cidx << 3) | (u ^ (cidx & 7))];
        }
      }
      floatx4 acc[2][8];
#pragma unroll
      for (int rt = 0; rt < 2; ++rt)
#pragma unroll
        for (int ct = 0; ct < 8; ++ct) acc[rt][ct] = (floatx4){0.f, 0.f, 0.f, 0.f};
#pragma unroll
      for (int kh = 0; kh < 2; ++kh)
#pragma unroll
        for (int ct = 0; ct < 8; ++ct)
#pragma unroll
          for (int rt = 0; rt < 2; ++rt)
            acc[rt][ct] = __builtin_amdgcn_mfma_f32_16x16x32_bf16(
                af[rt][kh], bfr[ct][kh], acc[rt][ct], 0, 0, 0);
      // masked epilogue
#pragma unroll
      for (int rt = 0; rt < 2; ++rt) {
        const int rbase = rc * 128 + w * 32 + rt * 16 + quad * 4;
#pragma unroll
        for (int ct = 0; ct < 8; ++ct) {
#pragma unroll
          for (int r = 0; r < 4; ++r) {
            const bool ok = cvalid[ct] && (rbase + r < cntE);
            const float s = acc[rt][ct][r];
            const float d = __builtin_fmaf(s, LN2, -1.f);  // true sim - 1
            pos += ok ? d * d : 0.f;
            ngrow_acc[rt][r] += ok ? exp2_raw(s) : 0.f;  // bit-matches rowsum
          }
        }
      }
    }
    // per-row: subtract from total, log, accumulate
#pragma unroll
    for (int rt = 0; rt < 2; ++rt)
#pragma unroll
      for (int r = 0; r < 4; ++r) {
        float g = ngrow_acc[rt][r];
#pragma unroll
        for (int m = 1; m < 16; m <<= 1) g += __shfl_xor(g, m, 64);
        const int ridx = rc * 128 + w * 32 + rt * 16 + quad * 4 + r;
        if (l15 == 0 && ridx < cntE) {
          const float nf = negtot[bN + list[ridx]] - g;
          lns += __logf(fmaxf(nf, 1e-30f));
        }
      }
    // block reduction
#pragma unroll
    for (int m = 1; m < 64; m <<= 1) {
      pos += __shfl_xor(pos, m, 64);
      lns += __shfl_xor(lns, m, 64);
    }
    if (lane == 0) {
      sPos[w] = pos;
      sLn[w] = lns;
    }
    __syncthreads();
    if (t == 0) {
      const float pt = sPos[0] + sPos[1] + sPos[2] + sPos[3];
      const float lt = sLn[0] + sLn[1] + sLn[2] + sLn[3];
      const float c = (float)cnt;
      // partial (this row-chunk's rows); denominators are per-instance
      atomicAdd(accum, WPc * pt / (c * c) + (1.f - WPc) * lt / c);
    }
  }
  if (t == 0) {
    __threadfence();
    const int old = atomicAdd(ticket, 1);
    if (old == GBLK - 1) {
      const float tot = atomicAdd(accum, 0.f);  // atomic read sees all adds
      out[0] = tot / (float)(Bsz * Isz);
    }
  }
}

// ---------------------------------------------------------------------------
extern "C" void kernel_launch(void* const* d_in, const int* in_sizes, int n_in,
                              void* d_out, int out_size, void* d_ws,
                              size_t ws_size, hipStream_t stream) {
  const float* x = (const float*)d_in[0];          // [B,N,D] fp32
  const uint8_t* label = (const uint8_t*)d_in[1];  // [B,I,N] bool
  float* out = (float*)d_out;

  // Workspace: [xbf 2MB frag-ordered][negtot BN f32][accum][ticket]
  uint4* xbf = (uint4*)d_ws;
  float* negtot = (float*)(xbf + (size_t)Bsz * Nsz * Dsz / 8);
  float* accum = negtot + Bsz * Nsz;
  int* ticket = (int*)(accum + 1);

  prep_kernel<<<512, 256, 0, stream>>>(x, xbf, negtot, accum, ticket);

  // 136 supertiles (16 diag + 120 lower-triangle) x 4 row-chunks per batch
  dim3 gridA(544, Bsz);
  rowsum_sym_kernel<<<gridA, 64, 0, stream>>>(xbf, negtot);

  dim3 gridB(Isz, Bsz, 2);
  gram2_kernel<<<gridB, 256, 0, stream>>>(xbf, label, negtot, accum, ticket, out);
}